// Round 2
// baseline (1978.382 us; speedup 1.0000x reference)
//
#include <hip/hip_runtime.h>
#include <stdint.h>

#define DEV __device__ __forceinline__

typedef __bf16 bf16x8 __attribute__((ext_vector_type(8)));
typedef float  f32x4  __attribute__((ext_vector_type(4)));

// ---- model dims ----
// B=128, SEQ=1024, ENC=64, D=512, SEG=64, SNX=16, PRED=512, SNY=8
// N_enc = 8192 rows; N_dec = 65536 rows

DEV unsigned short f2bf(float f){
  union { float f; uint32_t u; } v; v.f = f;
  uint32_t r = (v.u + 0x7FFFu + ((v.u >> 16) & 1u)) >> 16;
  return (unsigned short)r;
}
DEV float bf2f(unsigned short s){
  union { uint32_t u; float f; } v; v.u = ((uint32_t)s) << 16; return v.f;
}
DEV float sigm(float x){ return 1.0f/(1.0f + __expf(-x)); }
DEV float tanhe(float x){ return 1.0f - 2.0f/(__expf(2.0f*x) + 1.0f); }

#define AS1(p) ((const __attribute__((address_space(1))) uint32_t*)(p))
#define AS3(p) ((__attribute__((address_space(3))) uint32_t*)(p))

// stage NROWS x 64 bf16 tile (row stride ld elems) into LINEAR LDS [NROWS][64]
// via global_load_lds width-16. NW waves; LDS base wave-uniform per chunk.
template<int NROWS, int NW>
DEV void gstage(const unsigned short* src, int ld, unsigned short* lds, int tid){
  constexpr int CH = NROWS/8;        // 1KB chunks (8 rows each)
  constexpr int PW = CH/NW;          // chunks per wave
  int wid = tid >> 6, lane = tid & 63;
  #pragma unroll
  for (int r = 0; r < PW; r++){
    int chunk = wid*PW + r;
    int row = chunk*8 + (lane >> 3);
    const unsigned short* g = src + (size_t)row*ld + (lane & 7)*8;
    unsigned short* l = lds + chunk*512;   // 1024 B
    __builtin_amdgcn_global_load_lds(AS1(g), AS3(l), 16, 0, 0);
  }
}

// wave-tile 32x64 over A[128][64], B[64][64] linear LDS. wm0 = wid*32.
DEV void mmaW(const unsigned short* As, const unsigned short* Bs, int wm0,
              int lane, f32x4 (&acc)[2][4]){
  int lr = lane & 15, lk = (lane >> 4)*8;
  #pragma unroll
  for (int ks = 0; ks < 2; ks++){
    int ko = ks*32 + lk;
    bf16x8 a[2], b[4];
    #pragma unroll
    for (int m = 0; m < 2; m++)
      a[m] = *reinterpret_cast<const bf16x8*>(&As[(wm0 + m*16 + lr)*64 + ko]);
    #pragma unroll
    for (int n = 0; n < 4; n++)
      b[n] = *reinterpret_cast<const bf16x8*>(&Bs[(n*16 + lr)*64 + ko]);
    #pragma unroll
    for (int m = 0; m < 2; m++)
      #pragma unroll
      for (int n = 0; n < 4; n++)
        acc[m][n] = __builtin_amdgcn_mfma_f32_16x16x32_bf16(a[m], b[n], acc[m][n], 0, 0, 0);
  }
}

// K=512 loop: A (128 rows, ld 512), B (64 rows, ld 512)
DEV void kloopW(const unsigned short* A0, const unsigned short* B0,
                unsigned short* As, unsigned short* Bs, int tid, int wm0, int lane,
                f32x4 (&acc)[2][4]){
  for (int kt = 0; kt < 8; kt++){
    gstage<128,4>(A0 + kt*64, 512, As, tid);
    gstage<64,4>(B0 + kt*64, 512, Bs, tid);
    __syncthreads();
    mmaW(As, Bs, wm0, lane, acc);
    __syncthreads();
  }
}

DEV void zero24(f32x4 (&a)[2][4]){
  f32x4 z = {0.f,0.f,0.f,0.f};
  #pragma unroll
  for (int m = 0; m < 2; m++)
    #pragma unroll
    for (int n = 0; n < 4; n++) a[m][n] = z;
}

// ---------------- one-shot prep kernels ----------------
__global__ __launch_bounds__(256) void cvt_all_kernel(
    const float* cWih, const float* cWhh, const float* gWih, const float* gWhh,
    const float* resW, const float* predW, const float* Wemb,
    unsigned short* o0, unsigned short* o1, unsigned short* o2, unsigned short* o3,
    unsigned short* o4, unsigned short* o5, unsigned short* o6){
  int g = blockIdx.x*256 + threadIdx.x;   // group of 4 f32
  const float* s; unsigned short* d; int idx;
  if      (g < 196608){ s=cWih;  d=o0; idx=g; }
  else if (g < 393216){ s=cWhh;  d=o1; idx=g-196608; }
  else if (g < 589824){ s=gWih;  d=o2; idx=g-393216; }
  else if (g < 786432){ s=gWhh;  d=o3; idx=g-589824; }
  else if (g < 851968){ s=resW;  d=o4; idx=g-786432; }
  else if (g < 860160){ s=predW; d=o5; idx=g-851968; }
  else if (g < 868352){ s=Wemb;  d=o6; idx=g-860160; }
  else return;
  float4 v = reinterpret_cast<const float4*>(s)[idx];
  ushort4 r; r.x=f2bf(v.x); r.y=f2bf(v.y); r.z=f2bf(v.z); r.w=f2bf(v.w);
  reinterpret_cast<ushort4*>(d)[idx] = r;
}

__global__ __launch_bounds__(256) void build_pe_kernel(const float* pos, const float* chan, unsigned short* pe){
  int i = blockIdx.x*256 + threadIdx.x;   // 262144 total
  if (i >= 512*512) return;
  int m = i >> 9, d = i & 511;
  int c = m >> 3, sy = m & 7;
  float v = (d < 256) ? pos[sy*256 + d] : chan[c*256 + (d-256)];
  pe[i] = f2bf(v);
}

// xs_all[n][tk] = bf16(x[b,tk,c] - x[b,1023,c]),  n = b*64+c.  Transpose via LDS.
__global__ __launch_bounds__(256) void xs_kernel(const float* __restrict__ x,
                                                 unsigned short* __restrict__ xs){
  __shared__ float tile[64][65];
  __shared__ float lastv[64];
  int b = blockIdx.y, tk0 = blockIdx.x*64, tid = threadIdx.x;
  if (tid < 64) lastv[tid] = x[(size_t)b*65536 + 65472 + tid];
  #pragma unroll
  for (int k = 0; k < 16; k++){
    int id = tid + k*256;
    int i = id >> 6, c = id & 63;
    tile[i][c] = x[(size_t)b*65536 + (size_t)(tk0+i)*64 + c];
  }
  __syncthreads();
  #pragma unroll
  for (int k = 0; k < 16; k++){
    int id = tid + k*256;
    int c = id >> 6, i = id & 63;
    xs[(size_t)(b*64 + c)*1024 + tk0 + i] = f2bf(tile[i][c] - lastv[c]);
  }
}

// ---------------- embedding GEMM: emb = silu(xs_t @ Wemb^T + b) ----------------
__global__ __launch_bounds__(256) void embed_kernel(const unsigned short* __restrict__ xs,
    const unsigned short* __restrict__ wemb, const float* __restrict__ bemb,
    unsigned short* __restrict__ embout, int t0, size_t zs){
  __shared__ unsigned short As[128*64];
  __shared__ unsigned short Bs[64*64];
  int tid = threadIdx.x, lane = tid & 63, wid = tid >> 6, wm0 = wid*32;
  int rA0 = blockIdx.x*128, d0 = blockIdx.y*64;
  int t = t0 + blockIdx.z;
  unsigned short* out = embout + (size_t)blockIdx.z * zs;

  gstage<128,4>(xs + (size_t)rA0*1024 + t*64, 1024, As, tid);
  gstage<64,4>(wemb + (size_t)d0*64, 64, Bs, tid);
  __syncthreads();
  f32x4 acc[2][4]; zero24(acc);
  mmaW(As, Bs, wm0, lane, acc);

  int lr = lane & 15, lj = (lane >> 4)*4;
  #pragma unroll
  for (int m = 0; m < 2; m++)
    #pragma unroll
    for (int n = 0; n < 4; n++){
      int col = d0 + n*16 + lr;
      float bb = bemb[col];
      #pragma unroll
      for (int j = 0; j < 4; j++){
        int row = rA0 + wm0 + m*16 + lj + j;
        float v = acc[m][n][j] + bb;
        v = v * sigm(v);
        out[(size_t)row*512 + col] = f2bf(v);
      }
    }
}

// ---------------- encoder gates -> h_cell (2 live accumulators) ----------------
__global__ __launch_bounds__(256) void gates_kernel(
    const unsigned short* __restrict__ emb, const unsigned short* __restrict__ hbf,
    const float* __restrict__ hf32,
    const unsigned short* __restrict__ Wih, const unsigned short* __restrict__ Whh,
    const float* __restrict__ bih, const float* __restrict__ bhh,
    unsigned short* __restrict__ hcell){
  __shared__ unsigned short As[128*64];
  __shared__ unsigned short Bs[64*64];
  int tid = threadIdx.x, lane = tid & 63, wid = tid >> 6, wm0 = wid*32;
  int rA0 = blockIdx.x*128, d0 = blockIdx.y*64;
  const unsigned short* Ae = emb + (size_t)rA0*512;
  const unsigned short* Ah = hbf + (size_t)rA0*512;
  int lr = lane & 15, lj = (lane >> 4)*4;

  f32x4 P[2][4], Q[2][4];

  // phase 1: rg preact = emb@WihR + h@WhhR   (gate rows d0)
  zero24(P);
  kloopW(Ae, Wih + (size_t)d0*512, As, Bs, tid, wm0, lane, P);
  kloopW(Ah, Whh + (size_t)d0*512, As, Bs, tid, wm0, lane, P);
  #pragma unroll
  for (int m = 0; m < 2; m++)
    #pragma unroll
    for (int n = 0; n < 4; n++){
      int col = d0 + n*16 + lr;
      float br = bih[col] + bhh[col];
      #pragma unroll
      for (int j = 0; j < 4; j++) P[m][n][j] = sigm(P[m][n][j] + br);
    }

  // phase 2: hn preact = h@WhhN ; P = rg * (hn + bnh)
  zero24(Q);
  kloopW(Ah, Whh + (size_t)(1024 + d0)*512, As, Bs, tid, wm0, lane, Q);
  #pragma unroll
  for (int m = 0; m < 2; m++)
    #pragma unroll
    for (int n = 0; n < 4; n++){
      int col = d0 + n*16 + lr;
      float bnh = bhh[1024 + col];
      #pragma unroll
      for (int j = 0; j < 4; j++) P[m][n][j] *= (Q[m][n][j] + bnh);
    }

  // phase 3: xn preact = emb@WihN ; P = tanh(xn + bni + P)  -> ng
  zero24(Q);
  kloopW(Ae, Wih + (size_t)(1024 + d0)*512, As, Bs, tid, wm0, lane, Q);
  #pragma unroll
  for (int m = 0; m < 2; m++)
    #pragma unroll
    for (int n = 0; n < 4; n++){
      int col = d0 + n*16 + lr;
      float bni = bih[1024 + col];
      #pragma unroll
      for (int j = 0; j < 4; j++) P[m][n][j] = tanhe(Q[m][n][j] + bni + P[m][n][j]);
    }

  // phase 4: zg preact ; h_cell = (1-zg)*ng + zg*h
  zero24(Q);
  kloopW(Ae, Wih + (size_t)(512 + d0)*512, As, Bs, tid, wm0, lane, Q);
  kloopW(Ah, Whh + (size_t)(512 + d0)*512, As, Bs, tid, wm0, lane, Q);
  #pragma unroll
  for (int m = 0; m < 2; m++)
    #pragma unroll
    for (int n = 0; n < 4; n++){
      int col = d0 + n*16 + lr;
      float bz = bih[512 + col] + bhh[512 + col];
      #pragma unroll
      for (int j = 0; j < 4; j++){
        float zg = sigm(Q[m][n][j] + bz);
        int row = rA0 + wm0 + m*16 + lj + j;
        float h = hf32[(size_t)row*512 + col];
        hcell[(size_t)row*512 + col] = f2bf((1.0f - zg)*P[m][n][j] + zg*h);
      }
    }
}

// ---------------- residual projection: h_new = emb + h_cell @ res_W^T + res_b ----------------
__global__ __launch_bounds__(256) void res_kernel(
    const unsigned short* __restrict__ hcell, const unsigned short* __restrict__ Wres,
    const float* __restrict__ res_b, const unsigned short* __restrict__ emb,
    float* __restrict__ hf32, unsigned short* __restrict__ hbf){
  __shared__ unsigned short As[128*64];
  __shared__ unsigned short Bs[64*64];
  int tid = threadIdx.x, lane = tid & 63, wid = tid >> 6, wm0 = wid*32;
  int rA0 = blockIdx.x*128, d0 = blockIdx.y*64;

  f32x4 acc[2][4]; zero24(acc);
  kloopW(hcell + (size_t)rA0*512, Wres + (size_t)d0*512, As, Bs, tid, wm0, lane, acc);

  int lr = lane & 15, lj = (lane >> 4)*4;
  #pragma unroll
  for (int m = 0; m < 2; m++)
    #pragma unroll
    for (int n = 0; n < 4; n++){
      int col = d0 + n*16 + lr;
      float bb = res_b[col];
      #pragma unroll
      for (int j = 0; j < 4; j++){
        int row = rA0 + wm0 + m*16 + lj + j;
        float v = acc[m][n][j] + bb + bf2f(emb[(size_t)row*512 + col]);
        hf32[(size_t)row*512 + col] = v;
        hbf[(size_t)row*512 + col]  = f2bf(v);
      }
    }
}

// ---------------- generic: C = A(Mx512) @ B^T + bias, f32 out ld=Nld ----------------
__global__ __launch_bounds__(256) void gemm_bias_kernel(
    const unsigned short* __restrict__ A, const unsigned short* __restrict__ B,
    const float* __restrict__ bias, float* __restrict__ C, int Nld){
  __shared__ unsigned short As[128*64];
  __shared__ unsigned short Bs[64*64];
  int tid = threadIdx.x, lane = tid & 63, wid = tid >> 6, wm0 = wid*32;
  int rA0 = blockIdx.x*128, rB0 = blockIdx.y*64;

  f32x4 acc[2][4]; zero24(acc);
  kloopW(A + (size_t)rA0*512, B + (size_t)rB0*512, As, Bs, tid, wm0, lane, acc);

  int lr = lane & 15, lj = (lane >> 4)*4;
  #pragma unroll
  for (int m = 0; m < 2; m++)
    #pragma unroll
    for (int n = 0; n < 4; n++){
      int col = rB0 + n*16 + lr;
      float bb = bias[col];
      #pragma unroll
      for (int j = 0; j < 4; j++){
        int row = rA0 + wm0 + m*16 + lj + j;
        C[(size_t)row*Nld + col] = acc[m][n][j] + bb;
      }
    }
}

// ---------------- decoder fuse: hy -> y -> out ----------------
DEV float hyf(float xr, float xz, float xn, float hr, float hz, float hn, float h){
  float rg = sigm(xr + hr);
  float zg = sigm(xz + hz);
  float ng = tanhe(xn + rg*hn);
  return (1.0f - zg)*ng + zg*h;
}

__global__ __launch_bounds__(256) void final_kernel(
    const float* __restrict__ gxd, const float* __restrict__ ghd,
    const float* __restrict__ hf32, const unsigned short* __restrict__ predW,
    const float* __restrict__ predb, const float* __restrict__ x,
    float* __restrict__ out){
  __shared__ unsigned short As[64*72];   // hy tile, padded
  __shared__ unsigned short Bs[64*64];   // predW tile, linear (gstage)
  int tid = threadIdx.x, lane = tid & 63, wid = tid >> 6;
  int r0 = blockIdx.x*64;

  // per-thread fixed row for the hy build
  int rl = tid >> 2, q = tid & 3;
  int rr = r0 + rl, nn0 = rr >> 3, sy0 = rr & 7, c0 = nn0 & 63, mpe = c0*8 + sy0;
  (void)sy0;
  const float* gx = gxd + (size_t)mpe*1536;
  const float* gh = ghd + (size_t)nn0*1536;
  const float* hp = hf32 + (size_t)nn0*512;

  f32x4 z4 = {0.f,0.f,0.f,0.f};
  f32x4 acc[4];
  #pragma unroll
  for (int n = 0; n < 4; n++) acc[n] = z4;

  for (int kt = 0; kt < 8; kt++){
    int dq = kt*64 + q*16;
    #pragma unroll
    for (int u = 0; u < 4; u++){
      int d = dq + u*4;
      float4 xr4 = *reinterpret_cast<const float4*>(gx + d);
      float4 xz4 = *reinterpret_cast<const float4*>(gx + 512 + d);
      float4 xn4 = *reinterpret_cast<const float4*>(gx + 1024 + d);
      float4 hr4 = *reinterpret_cast<const float4*>(gh + d);
      float4 hz4 = *reinterpret_cast<const float4*>(gh + 512 + d);
      float4 hn4 = *reinterpret_cast<const float4*>(gh + 1024 + d);
      float4 h4  = *reinterpret_cast<const float4*>(hp + d);
      ushort4 w;
      w.x = f2bf(hyf(xr4.x, xz4.x, xn4.x, hr4.x, hz4.x, hn4.x, h4.x));
      w.y = f2bf(hyf(xr4.y, xz4.y, xn4.y, hr4.y, hz4.y, hn4.y, h4.y));
      w.z = f2bf(hyf(xr4.z, xz4.z, xn4.z, hr4.z, hz4.z, hn4.z, h4.z));
      w.w = f2bf(hyf(xr4.w, xz4.w, xn4.w, hr4.w, hz4.w, hn4.w, h4.w));
      *reinterpret_cast<ushort4*>(&As[rl*72 + q*16 + u*4]) = w;
    }
    gstage<64,4>(predW + kt*64, 512, Bs, tid);
    __syncthreads();

    int lr = lane & 15, lk = (lane >> 4)*8;
    #pragma unroll
    for (int ks = 0; ks < 2; ks++){
      int ko = ks*32 + lk;
      bf16x8 a = *reinterpret_cast<const bf16x8*>(&As[(wid*16 + lr)*72 + ko]);
      #pragma unroll
      for (int n = 0; n < 4; n++){
        bf16x8 b = *reinterpret_cast<const bf16x8*>(&Bs[(n*16 + lr)*64 + ko]);
        acc[n] = __builtin_amdgcn_mfma_f32_16x16x32_bf16(a, b, acc[n], 0, 0, 0);
      }
    }
    __syncthreads();
  }

  int lr = lane & 15, lj = (lane >> 4)*4;
  #pragma unroll
  for (int n = 0; n < 4; n++){
    int s = n*16 + lr;
    float bb = predb[s];
    #pragma unroll
    for (int j = 0; j < 4; j++){
      int r = r0 + wid*16 + lj + j;
      int nn = r >> 3, sy = r & 7, b = nn >> 6, c = nn & 63;
      out[(size_t)b*32768 + (size_t)(sy*64 + s)*64 + c] =
          acc[n][j] + bb + x[(size_t)b*65536 + 65472 + c];
    }
  }
}

// ---------------- host ----------------
extern "C" void kernel_launch(void* const* d_in, const int* in_sizes, int n_in,
                              void* d_out, int out_size, void* d_ws, size_t ws_size,
                              hipStream_t stream){
  (void)in_sizes; (void)n_in; (void)out_size;
  const float* x     = (const float*)d_in[0];
  const float* Wemb  = (const float*)d_in[1];
  const float* bemb  = (const float*)d_in[2];
  const float* cWih  = (const float*)d_in[3];
  const float* cWhh  = (const float*)d_in[4];
  const float* cbih  = (const float*)d_in[5];
  const float* cbhh  = (const float*)d_in[6];
  const float* gWih  = (const float*)d_in[7];
  const float* gWhh  = (const float*)d_in[8];
  const float* gbih  = (const float*)d_in[9];
  const float* gbhh  = (const float*)d_in[10];
  const float* resW  = (const float*)d_in[11];
  const float* resb  = (const float*)d_in[12];
  const float* pos   = (const float*)d_in[13];
  const float* chan  = (const float*)d_in[14];
  const float* predW = (const float*)d_in[15];
  const float* predb = (const float*)d_in[16];
  float* out = (float*)d_out;

  uint8_t* ws = (uint8_t*)d_ws;
  size_t o = 0;
  auto take = [&](size_t bytes){ uint8_t* p = ws + o; o += (bytes + 255) & ~(size_t)255; return p; };
  unsigned short* wb_cWih  = (unsigned short*)take(786432*2);
  unsigned short* wb_cWhh  = (unsigned short*)take(786432*2);
  unsigned short* wb_gWih  = (unsigned short*)take(786432*2);
  unsigned short* wb_gWhh  = (unsigned short*)take(786432*2);
  unsigned short* wb_resW  = (unsigned short*)take(262144*2);
  unsigned short* wb_predW = (unsigned short*)take(32768*2);
  unsigned short* wb_Wemb  = (unsigned short*)take(32768*2);
  unsigned short* pe_bf    = (unsigned short*)take(262144*2);
  float*          h_f32    = (float*)take(4194304*4);
  unsigned short* h_bf     = (unsigned short*)take(4194304*2);

  // union region: encoder {xs_all, hcell, emb} / decoder {ghd, gxd}
  uint8_t* U = ws + o;
  unsigned short* xs_all = (unsigned short*)(U);
  unsigned short* hcell  = (unsigned short*)(U + 16777216);
  unsigned short* emb    = (unsigned short*)(U + 16777216 + 8388608);
  float*          ghd    = (float*)(U);
  float*          gxd    = (float*)(U + 50331648);

  // big path: all 16 embeddings precomputed in one launch (needs ~193 MB total)
  bool big = ws_size >= o + (size_t)16777216 + 8388608 + (size_t)16*8388608;
  size_t zs = big ? 4194304 : 0;

  cvt_all_kernel<<<3392, 256, 0, stream>>>(cWih, cWhh, gWih, gWhh, resW, predW, Wemb,
      wb_cWih, wb_cWhh, wb_gWih, wb_gWhh, wb_resW, wb_predW, wb_Wemb);
  build_pe_kernel<<<1024, 256, 0, stream>>>(pos, chan, pe_bf);
  xs_kernel<<<dim3(16, 128), 256, 0, stream>>>(x, xs_all);
  hipMemsetAsync(h_f32, 0, (size_t)4194304*4, stream);
  hipMemsetAsync(h_bf,  0, (size_t)4194304*2, stream);

  if (big)
    embed_kernel<<<dim3(64, 8, 16), 256, 0, stream>>>(xs_all, wb_Wemb, bemb, emb, 0, zs);

  for (int t = 0; t < 16; t++){
    const unsigned short* emb_t = emb + (big ? (size_t)t*4194304 : 0);
    if (!big)
      embed_kernel<<<dim3(64, 8, 1), 256, 0, stream>>>(xs_all, wb_Wemb, bemb,
                                                       (unsigned short*)emb_t, t, 0);
    gates_kernel<<<dim3(64, 8), 256, 0, stream>>>(emb_t, h_bf, h_f32, wb_cWih, wb_cWhh,
                                                  cbih, cbhh, hcell);
    res_kernel<<<dim3(64, 8), 256, 0, stream>>>(hcell, wb_resW, resb, emb_t, h_f32, h_bf);
  }

  // decoder: ghd = hn @ gru_Whh^T + gbhh ; gxd = pe @ gru_Wih^T + gbih
  gemm_bias_kernel<<<dim3(64, 24), 256, 0, stream>>>(h_bf,  wb_gWhh, gbhh, ghd, 1536);
  gemm_bias_kernel<<<dim3(4, 24),  256, 0, stream>>>(pe_bf, wb_gWih, gbih, gxd, 1536);

  final_kernel<<<1024, 256, 0, stream>>>(gxd, ghd, h_f32, wb_predW, predb, x, out);
}

// Round 3
// 1182.305 us; speedup vs baseline: 1.6733x; 1.6733x over previous
//
#include <hip/hip_runtime.h>
#include <stdint.h>

#define DEV __device__ __forceinline__

typedef __bf16 bf16x8 __attribute__((ext_vector_type(8)));
typedef float  f32x4  __attribute__((ext_vector_type(4)));

// ---- model dims ----
// B=128, SEQ=1024, ENC=64, D=512, SEG=64, SNX=16, PRED=512, SNY=8
// N_enc = 8192 rows; N_dec = 65536 rows

DEV unsigned short f2bf(float f){
  union { float f; uint32_t u; } v; v.f = f;
  uint32_t r = (v.u + 0x7FFFu + ((v.u >> 16) & 1u)) >> 16;
  return (unsigned short)r;
}
DEV float bf2f(unsigned short s){
  union { uint32_t u; float f; } v; v.u = ((uint32_t)s) << 16; return v.f;
}
DEV float sigm(float x){ return 1.0f/(1.0f + __expf(-x)); }
DEV float tanhe(float x){ return 1.0f - 2.0f/(__expf(2.0f*x) + 1.0f); }

#define AS1(p) ((const __attribute__((address_space(1))) uint32_t*)(p))
#define AS3(p) ((__attribute__((address_space(3))) uint32_t*)(p))

// Stage NROWS x 64 bf16 (row stride ld) into LDS [NROWS][64] via global_load_lds,
// with XOR-swizzled SOURCE: LDS slot s of row r holds global slot s^(r&7).
// Readers must XOR their k-offset with ((row&7)<<3). (rule 21 / m173 pattern)
template<int NROWS, int NW>
DEV void gstage(const unsigned short* src, int ld, unsigned short* lds, int tid){
  constexpr int CH = NROWS/8;        // 1KB chunks (8 rows each)
  constexpr int PW = CH/NW;          // chunks per wave
  int wid = tid >> 6, lane = tid & 63;
  int rsub = lane >> 3;              // row within chunk (== row&7)
  int slot = (lane & 7) ^ rsub;      // pre-swizzled global 16B slot
  #pragma unroll
  for (int r = 0; r < PW; r++){
    int chunk = wid*PW + r;
    int row = chunk*8 + rsub;
    __builtin_amdgcn_global_load_lds(AS1(src + (size_t)row*ld + slot*8),
                                     AS3(lds + chunk*512), 16, 0, 0);
  }
}

// wave-tile 32x64 over A[128][64], B[64][64] swizzled LDS. wm0 = wid*32.
DEV void mmaW(const unsigned short* As, const unsigned short* Bs, int wm0,
              int lane, f32x4 (&acc)[2][4]){
  int lr = lane & 15, lk = (lane >> 4)*8, sw = (lane & 7) << 3;
  #pragma unroll
  for (int ks = 0; ks < 2; ks++){
    int ko = (ks*32 + lk) ^ sw;      // row&7 == lane&7 for all rows read below
    bf16x8 a[2], b[4];
    #pragma unroll
    for (int m = 0; m < 2; m++)
      a[m] = *reinterpret_cast<const bf16x8*>(&As[(wm0 + m*16 + lr)*64 + ko]);
    #pragma unroll
    for (int n = 0; n < 4; n++)
      b[n] = *reinterpret_cast<const bf16x8*>(&Bs[(n*16 + lr)*64 + ko]);
    #pragma unroll
    for (int m = 0; m < 2; m++)
      #pragma unroll
      for (int n = 0; n < 4; n++)
        acc[m][n] = __builtin_amdgcn_mfma_f32_16x16x32_bf16(a[m], b[n], acc[m][n], 0, 0, 0);
  }
}

DEV void zero24(f32x4 (&a)[2][4]){
  f32x4 z = {0.f,0.f,0.f,0.f};
  #pragma unroll
  for (int m = 0; m < 2; m++)
    #pragma unroll
    for (int n = 0; n < 4; n++) a[m][n] = z;
}

// Double-buffered K-loop over NSEG segments of 8 k-tiles (K=64 each), lda=ldb=512.
// One barrier per tile; stage of tile i+1 overlaps MFMA of tile i.
// AsB: 2 x 8192 elems, BsB: 2 x 4096 elems. Trailing barrier elided (see callers).
template<int NSEG>
DEV void kloopD(const unsigned short* A0, const unsigned short* B0,
                const unsigned short* A1, const unsigned short* B1,
                unsigned short* AsB, unsigned short* BsB,
                int tid, int wm0, int lane, f32x4 (&acc)[2][4]){
  constexpr int NT = NSEG*8;
  gstage<128,4>(A0, 512, AsB, tid);
  gstage<64,4>(B0, 512, BsB, tid);
  __syncthreads();
  #pragma unroll 2
  for (int i = 0; i < NT; i++){
    int cur = i & 1;
    if (i + 1 < NT){
      int j = i + 1;
      const unsigned short* Aj = (NSEG == 2 && j >= 8) ? A1 : A0;
      const unsigned short* Bj = (NSEG == 2 && j >= 8) ? B1 : B0;
      int jo = (j & 7)*64;
      gstage<128,4>(Aj + jo, 512, AsB + (cur^1)*8192, tid);
      gstage<64,4>(Bj + jo, 512, BsB + (cur^1)*4096, tid);
    }
    mmaW(AsB + cur*8192, BsB + cur*4096, wm0, lane, acc);
    if (i + 1 < NT) __syncthreads();
  }
}

// ---------------- one-shot prep kernels ----------------
__global__ __launch_bounds__(256) void cvt_all_kernel(
    const float* cWih, const float* cWhh, const float* gWih, const float* gWhh,
    const float* resW, const float* predW, const float* Wemb,
    unsigned short* o0, unsigned short* o1, unsigned short* o2, unsigned short* o3,
    unsigned short* o4, unsigned short* o5, unsigned short* o6){
  int g = blockIdx.x*256 + threadIdx.x;   // group of 4 f32
  const float* s; unsigned short* d; int idx;
  if      (g < 196608){ s=cWih;  d=o0; idx=g; }
  else if (g < 393216){ s=cWhh;  d=o1; idx=g-196608; }
  else if (g < 589824){ s=gWih;  d=o2; idx=g-393216; }
  else if (g < 786432){ s=gWhh;  d=o3; idx=g-589824; }
  else if (g < 851968){ s=resW;  d=o4; idx=g-786432; }
  else if (g < 860160){ s=predW; d=o5; idx=g-851968; }
  else if (g < 868352){ s=Wemb;  d=o6; idx=g-860160; }
  else return;
  float4 v = reinterpret_cast<const float4*>(s)[idx];
  ushort4 r; r.x=f2bf(v.x); r.y=f2bf(v.y); r.z=f2bf(v.z); r.w=f2bf(v.w);
  reinterpret_cast<ushort4*>(d)[idx] = r;
}

__global__ __launch_bounds__(256) void build_pe_kernel(const float* pos, const float* chan, unsigned short* pe){
  int i = blockIdx.x*256 + threadIdx.x;   // 262144 total
  if (i >= 512*512) return;
  int m = i >> 9, d = i & 511;
  int c = m >> 3, sy = m & 7;
  float v = (d < 256) ? pos[sy*256 + d] : chan[c*256 + (d-256)];
  pe[i] = f2bf(v);
}

// xs_all[n][tk] = bf16(x[b,tk,c] - x[b,1023,c]),  n = b*64+c.  Transpose via LDS.
__global__ __launch_bounds__(256) void xs_kernel(const float* __restrict__ x,
                                                 unsigned short* __restrict__ xs){
  __shared__ float tile[64][65];
  __shared__ float lastv[64];
  int b = blockIdx.y, tk0 = blockIdx.x*64, tid = threadIdx.x;
  if (tid < 64) lastv[tid] = x[(size_t)b*65536 + 65472 + tid];
  #pragma unroll
  for (int k = 0; k < 16; k++){
    int id = tid + k*256;
    int i = id >> 6, c = id & 63;
    tile[i][c] = x[(size_t)b*65536 + (size_t)(tk0+i)*64 + c];
  }
  __syncthreads();
  #pragma unroll
  for (int k = 0; k < 16; k++){
    int id = tid + k*256;
    int c = id >> 6, i = id & 63;
    xs[(size_t)(b*64 + c)*1024 + tk0 + i] = f2bf(tile[i][c] - lastv[c]);
  }
}

// ---------------- embedding GEMM: emb = silu(xs_t @ Wemb^T + b) ----------------
__global__ __launch_bounds__(256) void embed_kernel(const unsigned short* __restrict__ xs,
    const unsigned short* __restrict__ wemb, const float* __restrict__ bemb,
    unsigned short* __restrict__ embout, int t0, size_t zs){
  __shared__ unsigned short As[128*64];
  __shared__ unsigned short Bs[64*64];
  int tid = threadIdx.x, lane = tid & 63, wid = tid >> 6, wm0 = wid*32;
  int rA0 = blockIdx.x*128, d0 = blockIdx.y*64;
  int t = t0 + blockIdx.z;
  unsigned short* out = embout + (size_t)blockIdx.z * zs;

  gstage<128,4>(xs + (size_t)rA0*1024 + t*64, 1024, As, tid);
  gstage<64,4>(wemb + (size_t)d0*64, 64, Bs, tid);
  __syncthreads();
  f32x4 acc[2][4]; zero24(acc);
  mmaW(As, Bs, wm0, lane, acc);

  int lr = lane & 15, lj = (lane >> 4)*4;
  #pragma unroll
  for (int m = 0; m < 2; m++)
    #pragma unroll
    for (int n = 0; n < 4; n++){
      int col = d0 + n*16 + lr;
      float bb = bemb[col];
      #pragma unroll
      for (int j = 0; j < 4; j++){
        int row = rA0 + wm0 + m*16 + lj + j;
        float v = acc[m][n][j] + bb;
        v = v * sigm(v);
        out[(size_t)row*512 + col] = f2bf(v);
      }
    }
}

// ---------------- encoder gates -> h_cell ----------------
__global__ __launch_bounds__(256) void gates_kernel(
    const unsigned short* __restrict__ emb, const unsigned short* __restrict__ hbf,
    const float* __restrict__ hf32,
    const unsigned short* __restrict__ Wih, const unsigned short* __restrict__ Whh,
    const float* __restrict__ bih, const float* __restrict__ bhh,
    unsigned short* __restrict__ hcell){
  __shared__ unsigned short As[2*128*64];
  __shared__ unsigned short Bs[2*64*64];
  int tid = threadIdx.x, lane = tid & 63, wid = tid >> 6, wm0 = wid*32;
  int rA0 = blockIdx.x*128, d0 = blockIdx.y*64;
  const unsigned short* Ae = emb + (size_t)rA0*512;
  const unsigned short* Ah = hbf + (size_t)rA0*512;
  int lr = lane & 15, lj = (lane >> 4)*4;

  f32x4 P[2][4], Q[2][4];

  // phase 1: rg = sigm(emb@WihR + h@WhhR + br)
  zero24(P);
  kloopD<2>(Ae, Wih + (size_t)d0*512, Ah, Whh + (size_t)d0*512, As, Bs, tid, wm0, lane, P);
  #pragma unroll
  for (int m = 0; m < 2; m++)
    #pragma unroll
    for (int n = 0; n < 4; n++){
      int col = d0 + n*16 + lr;
      float br = bih[col] + bhh[col];
      #pragma unroll
      for (int j = 0; j < 4; j++) P[m][n][j] = sigm(P[m][n][j] + br);
    }

  // phase 2: hn-pre = h@WhhN ; P = rg * (hn + bnh)
  zero24(Q);
  kloopD<1>(Ah, Whh + (size_t)(1024 + d0)*512, nullptr, nullptr, As, Bs, tid, wm0, lane, Q);
  #pragma unroll
  for (int m = 0; m < 2; m++)
    #pragma unroll
    for (int n = 0; n < 4; n++){
      float bnh = bhh[1024 + d0 + n*16 + lr];
      #pragma unroll
      for (int j = 0; j < 4; j++) P[m][n][j] *= (Q[m][n][j] + bnh);
    }

  // phase 3: xn-pre = emb@WihN ; P = tanh(xn + bni + P)  -> ng
  zero24(Q);
  kloopD<1>(Ae, Wih + (size_t)(1024 + d0)*512, nullptr, nullptr, As, Bs, tid, wm0, lane, Q);
  #pragma unroll
  for (int m = 0; m < 2; m++)
    #pragma unroll
    for (int n = 0; n < 4; n++){
      float bni = bih[1024 + d0 + n*16 + lr];
      #pragma unroll
      for (int j = 0; j < 4; j++) P[m][n][j] = tanhe(Q[m][n][j] + bni + P[m][n][j]);
    }

  // phase 4: zg-pre ; h_cell = (1-zg)*ng + zg*h
  zero24(Q);
  kloopD<2>(Ae, Wih + (size_t)(512 + d0)*512, Ah, Whh + (size_t)(512 + d0)*512,
            As, Bs, tid, wm0, lane, Q);
  #pragma unroll
  for (int m = 0; m < 2; m++)
    #pragma unroll
    for (int n = 0; n < 4; n++){
      int col = d0 + n*16 + lr;
      float bz = bih[512 + col] + bhh[512 + col];
      #pragma unroll
      for (int j = 0; j < 4; j++){
        float zg = sigm(Q[m][n][j] + bz);
        int row = rA0 + wm0 + m*16 + lj + j;
        float h = hf32[(size_t)row*512 + col];
        hcell[(size_t)row*512 + col] = f2bf((1.0f - zg)*P[m][n][j] + zg*h);
      }
    }
}

// ---------------- residual projection: h_new = emb + h_cell @ res_W^T + res_b ----------------
__global__ __launch_bounds__(256) void res_kernel(
    const unsigned short* __restrict__ hcell, const unsigned short* __restrict__ Wres,
    const float* __restrict__ res_b, const unsigned short* __restrict__ emb,
    float* __restrict__ hf32, unsigned short* __restrict__ hbf){
  __shared__ unsigned short As[2*128*64];
  __shared__ unsigned short Bs[2*64*64];
  int tid = threadIdx.x, lane = tid & 63, wid = tid >> 6, wm0 = wid*32;
  int rA0 = blockIdx.x*128, d0 = blockIdx.y*64;

  f32x4 acc[2][4]; zero24(acc);
  kloopD<1>(hcell + (size_t)rA0*512, Wres + (size_t)d0*512, nullptr, nullptr,
            As, Bs, tid, wm0, lane, acc);

  int lr = lane & 15, lj = (lane >> 4)*4;
  #pragma unroll
  for (int m = 0; m < 2; m++)
    #pragma unroll
    for (int n = 0; n < 4; n++){
      int col = d0 + n*16 + lr;
      float bb = res_b[col];
      #pragma unroll
      for (int j = 0; j < 4; j++){
        int row = rA0 + wm0 + m*16 + lj + j;
        float v = acc[m][n][j] + bb + bf2f(emb[(size_t)row*512 + col]);
        hf32[(size_t)row*512 + col] = v;
        hbf[(size_t)row*512 + col]  = f2bf(v);
      }
    }
}

// ---------------- generic: C = A(Mx512) @ B^T + bias, f32 out ld=Nld ----------------
__global__ __launch_bounds__(256) void gemm_bias_kernel(
    const unsigned short* __restrict__ A, const unsigned short* __restrict__ B,
    const float* __restrict__ bias, float* __restrict__ C, int Nld){
  __shared__ unsigned short As[2*128*64];
  __shared__ unsigned short Bs[2*64*64];
  int tid = threadIdx.x, lane = tid & 63, wid = tid >> 6, wm0 = wid*32;
  int rA0 = blockIdx.x*128, rB0 = blockIdx.y*64;

  f32x4 acc[2][4]; zero24(acc);
  kloopD<1>(A + (size_t)rA0*512, B + (size_t)rB0*512, nullptr, nullptr,
            As, Bs, tid, wm0, lane, acc);

  int lr = lane & 15, lj = (lane >> 4)*4;
  #pragma unroll
  for (int m = 0; m < 2; m++)
    #pragma unroll
    for (int n = 0; n < 4; n++){
      int col = rB0 + n*16 + lr;
      float bb = bias[col];
      #pragma unroll
      for (int j = 0; j < 4; j++){
        int row = rA0 + wm0 + m*16 + lj + j;
        C[(size_t)row*Nld + col] = acc[m][n][j] + bb;
      }
    }
}

// ---------------- decoder fuse: hy -> y -> out ----------------
DEV float hyf(float xr, float xz, float xn, float hr, float hz, float hn, float h){
  float rg = sigm(xr + hr);
  float zg = sigm(xz + hz);
  float ng = tanhe(xn + rg*hn);
  return (1.0f - zg)*ng + zg*h;
}

__global__ __launch_bounds__(256) void final_kernel(
    const float* __restrict__ gxd, const float* __restrict__ ghd,
    const float* __restrict__ hf32, const unsigned short* __restrict__ predW,
    const float* __restrict__ predb, const float* __restrict__ x,
    float* __restrict__ out){
  __shared__ unsigned short As[2][64*72];   // hy tile, padded (ds_write staged)
  __shared__ unsigned short Bs[2][64*64];   // predW tile (gstage, swizzled)
  int tid = threadIdx.x, lane = tid & 63, wid = tid >> 6;
  int r0 = blockIdx.x*64;

  int rl = tid >> 2, q = tid & 3;
  int rr = r0 + rl, nn0 = rr >> 3, sy0 = rr & 7, c0 = nn0 & 63, mpe = c0*8 + sy0;
  const float* gx = gxd + (size_t)mpe*1536;
  const float* gh = ghd + (size_t)nn0*1536;
  const float* hp = hf32 + (size_t)nn0*512;

  auto build = [&](int kt, unsigned short* dst){
    int dq = kt*64 + q*16;
    #pragma unroll
    for (int u = 0; u < 4; u++){
      int d = dq + u*4;
      float4 xr4 = *reinterpret_cast<const float4*>(gx + d);
      float4 xz4 = *reinterpret_cast<const float4*>(gx + 512 + d);
      float4 xn4 = *reinterpret_cast<const float4*>(gx + 1024 + d);
      float4 hr4 = *reinterpret_cast<const float4*>(gh + d);
      float4 hz4 = *reinterpret_cast<const float4*>(gh + 512 + d);
      float4 hn4 = *reinterpret_cast<const float4*>(gh + 1024 + d);
      float4 h4  = *reinterpret_cast<const float4*>(hp + d);
      ushort4 w;
      w.x = f2bf(hyf(xr4.x, xz4.x, xn4.x, hr4.x, hz4.x, hn4.x, h4.x));
      w.y = f2bf(hyf(xr4.y, xz4.y, xn4.y, hr4.y, hz4.y, hn4.y, h4.y));
      w.z = f2bf(hyf(xr4.z, xz4.z, xn4.z, hr4.z, hz4.z, hn4.z, h4.z));
      w.w = f2bf(hyf(xr4.w, xz4.w, xn4.w, hr4.w, hz4.w, hn4.w, h4.w));
      *reinterpret_cast<ushort4*>(&dst[rl*72 + q*16 + u*4]) = w;
    }
  };

  f32x4 z4 = {0.f,0.f,0.f,0.f};
  f32x4 acc[4];
  #pragma unroll
  for (int n = 0; n < 4; n++) acc[n] = z4;

  build(0, As[0]);
  gstage<64,4>(predW, 512, Bs[0], tid);
  __syncthreads();

  int lr = lane & 15, lk = (lane >> 4)*8, sw = (lane & 7) << 3;
  #pragma unroll 2
  for (int kt = 0; kt < 8; kt++){
    int cur = kt & 1;
    if (kt < 7){
      build(kt + 1, As[cur^1]);
      gstage<64,4>(predW + (kt+1)*64, 512, Bs[cur^1], tid);
    }
    #pragma unroll
    for (int ks = 0; ks < 2; ks++){
      int ko = ks*32 + lk;
      int kob = ko ^ sw;
      bf16x8 a = *reinterpret_cast<const bf16x8*>(&As[cur][(wid*16 + lr)*72 + ko]);
      #pragma unroll
      for (int n = 0; n < 4; n++){
        bf16x8 b = *reinterpret_cast<const bf16x8*>(&Bs[cur][(n*16 + lr)*64 + kob]);
        acc[n] = __builtin_amdgcn_mfma_f32_16x16x32_bf16(a, b, acc[n], 0, 0, 0);
      }
    }
    if (kt < 7) __syncthreads();
  }

  int lj = (lane >> 4)*4;
  #pragma unroll
  for (int n = 0; n < 4; n++){
    int s = n*16 + lr;
    float bb = predb[s];
    #pragma unroll
    for (int j = 0; j < 4; j++){
      int r = r0 + wid*16 + lj + j;
      int nn = r >> 3, sy = r & 7, b = nn >> 6, c = nn & 63;
      out[(size_t)b*32768 + (size_t)(sy*64 + s)*64 + c] =
          acc[n][j] + bb + x[(size_t)b*65536 + 65472 + c];
    }
  }
}

// ---------------- host ----------------
extern "C" void kernel_launch(void* const* d_in, const int* in_sizes, int n_in,
                              void* d_out, int out_size, void* d_ws, size_t ws_size,
                              hipStream_t stream){
  (void)in_sizes; (void)n_in; (void)out_size;
  const float* x     = (const float*)d_in[0];
  const float* Wemb  = (const float*)d_in[1];
  const float* bemb  = (const float*)d_in[2];
  const float* cWih  = (const float*)d_in[3];
  const float* cWhh  = (const float*)d_in[4];
  const float* cbih  = (const float*)d_in[5];
  const float* cbhh  = (const float*)d_in[6];
  const float* gWih  = (const float*)d_in[7];
  const float* gWhh  = (const float*)d_in[8];
  const float* gbih  = (const float*)d_in[9];
  const float* gbhh  = (const float*)d_in[10];
  const float* resW  = (const float*)d_in[11];
  const float* resb  = (const float*)d_in[12];
  const float* pos   = (const float*)d_in[13];
  const float* chan  = (const float*)d_in[14];
  const float* predW = (const float*)d_in[15];
  const float* predb = (const float*)d_in[16];
  float* out = (float*)d_out;

  uint8_t* ws = (uint8_t*)d_ws;
  size_t o = 0;
  auto take = [&](size_t bytes){ uint8_t* p = ws + o; o += (bytes + 255) & ~(size_t)255; return p; };
  unsigned short* wb_cWih  = (unsigned short*)take(786432*2);
  unsigned short* wb_cWhh  = (unsigned short*)take(786432*2);
  unsigned short* wb_gWih  = (unsigned short*)take(786432*2);
  unsigned short* wb_gWhh  = (unsigned short*)take(786432*2);
  unsigned short* wb_resW  = (unsigned short*)take(262144*2);
  unsigned short* wb_predW = (unsigned short*)take(32768*2);
  unsigned short* wb_Wemb  = (unsigned short*)take(32768*2);
  unsigned short* pe_bf    = (unsigned short*)take(262144*2);
  float*          h_f32    = (float*)take(4194304*4);
  unsigned short* h_bf     = (unsigned short*)take(4194304*2);

  // union region: encoder {xs_all, hcell, emb} / decoder {ghd, gxd}
  uint8_t* U = ws + o;
  unsigned short* xs_all = (unsigned short*)(U);
  unsigned short* hcell  = (unsigned short*)(U + 16777216);
  unsigned short* emb    = (unsigned short*)(U + 16777216 + 8388608);
  float*          ghd    = (float*)(U);
  float*          gxd    = (float*)(U + 50331648);

  bool big = ws_size >= o + (size_t)16777216 + 8388608 + (size_t)16*8388608;
  size_t zs = big ? 4194304 : 0;

  cvt_all_kernel<<<3392, 256, 0, stream>>>(cWih, cWhh, gWih, gWhh, resW, predW, Wemb,
      wb_cWih, wb_cWhh, wb_gWih, wb_gWhh, wb_resW, wb_predW, wb_Wemb);
  build_pe_kernel<<<1024, 256, 0, stream>>>(pos, chan, pe_bf);
  xs_kernel<<<dim3(16, 128), 256, 0, stream>>>(x, xs_all);
  hipMemsetAsync(h_f32, 0, (size_t)4194304*4, stream);
  hipMemsetAsync(h_bf,  0, (size_t)4194304*2, stream);

  if (big)
    embed_kernel<<<dim3(64, 8, 16), 256, 0, stream>>>(xs_all, wb_Wemb, bemb, emb, 0, zs);

  for (int t = 0; t < 16; t++){
    const unsigned short* emb_t = emb + (big ? (size_t)t*4194304 : 0);
    if (!big)
      embed_kernel<<<dim3(64, 8, 1), 256, 0, stream>>>(xs_all, wb_Wemb, bemb,
                                                       (unsigned short*)emb_t, t, 0);
    gates_kernel<<<dim3(64, 8), 256, 0, stream>>>(emb_t, h_bf, h_f32, wb_cWih, wb_cWhh,
                                                  cbih, cbhh, hcell);
    res_kernel<<<dim3(64, 8), 256, 0, stream>>>(hcell, wb_resW, resb, emb_t, h_f32, h_bf);
  }

  gemm_bias_kernel<<<dim3(64, 24), 256, 0, stream>>>(h_bf,  wb_gWhh, gbhh, ghd, 1536);
  gemm_bias_kernel<<<dim3(4, 24),  256, 0, stream>>>(pe_bf, wb_gWih, gbih, gxd, 1536);

  final_kernel<<<1024, 256, 0, stream>>>(gxd, ghd, h_f32, wb_predW, predb, x, out);
}